// Round 7
// baseline (223.244 us; speedup 1.0000x reference)
//
#include <hip/hip_runtime.h>
#include <math.h>

#define B    32
#define INF  784
#define H1   1024
#define H2   1024
#define NC   10
#define EPSV 0.1f

typedef __attribute__((ext_vector_type(8))) short short8;
typedef __attribute__((ext_vector_type(4))) float floatx4;

__device__ inline ushort bf16_rne(float f) {
  uint u = __builtin_bit_cast(uint, f);
  u += 0x7FFFu + ((u >> 16) & 1u);
  return (ushort)(u >> 16);
}
__device__ inline uint pack2(float a, float b) {
  return (uint)bf16_rne(a) | ((uint)bf16_rne(b) << 16);
}
// scale a packed pair of bf16 (in dword u) by d0,d1 and repack (round-half-up,
// matches r4 numerics — do NOT change rounding)
__device__ inline uint scale_pack(uint u, float d0, float d1v) {
  float f0 = __builtin_bit_cast(float, u << 16) * d0;
  float f1 = __builtin_bit_cast(float, u & 0xFFFF0000u) * d1v;
  uint r0 = __builtin_bit_cast(uint, f0) + 0x8000u;
  uint r1 = __builtin_bit_cast(uint, f1) + 0x8000u;
  return __builtin_amdgcn_perm(r1, r0, 0x07060302u);
}

// ---------------------------------------------------------------------------
// K_PRE: merged preprocessing + zero-init.  (r2 structure, W1F stride 49)
//  [0,64):     W2F fragment pack
//  [64,113):   W1F fragment pack via LDS transpose (coalesced reads)
//  [113,1137): layer-1 row i = bid-113
//  [1137,1144): zero E/F/F2 region (54272 floats from E base)
// ---------------------------------------------------------------------------
__global__ __launch_bounds__(256) void k_pre(
    const float* __restrict__ x, const float* __restrict__ W1,
    const float* __restrict__ b1, const float* __restrict__ W2,
    ushort* __restrict__ W1F, ushort* __restrict__ W2F,
    float* __restrict__ d1B, float* __restrict__ t1B, float* __restrict__ dnB,
    float* __restrict__ Ezero)
{
  __shared__ float red[4][B + 1];
  __shared__ float Ts[4][32][17];
  int bid = blockIdx.x;
  int t = threadIdx.x;
  if (bid < 64) {
    int jt = bid;
    int lane = t & 63, c0 = t >> 6;
    int l15 = lane & 15, quad = lane >> 4;
    for (int c = c0; c < 32; c += 4) {
      const float* src = &W2[(size_t)(jt * 16 + l15) * H1 + c * 32 + quad * 8];
      float4 v0 = *reinterpret_cast<const float4*>(src);
      float4 v1 = *reinterpret_cast<const float4*>(src + 4);
      uint4 o;
      o.x = pack2(v0.x, v0.y); o.y = pack2(v0.z, v0.w);
      o.z = pack2(v1.x, v1.y); o.w = pack2(v1.z, v1.w);
      *reinterpret_cast<uint4*>(&W2F[((size_t)(c * 64 + jt) * 64 + lane) * 8]) = o;
    }
  } else if (bid < 113) {
    int mt = bid - 64;
    int col0 = mt * 16;
    int w = t >> 6, lane = t & 63;
    int l15 = lane & 15, quad = lane >> 4;
    for (int cg = 0; cg < 8; cg++) {
      int c = cg * 4 + w;
#pragma unroll
      for (int p = 0; p < 8; p++) {
        int r = p * 4 + (lane >> 4);
        Ts[w][r][lane & 15] = W1[(size_t)(c * 32 + r) * INF + col0 + (lane & 15)];
      }
      float f[8];
#pragma unroll
      for (int e = 0; e < 8; e++) f[e] = Ts[w][quad * 8 + e][l15];
      uint4 o;
      o.x = pack2(f[0], f[1]); o.y = pack2(f[2], f[3]);
      o.z = pack2(f[4], f[5]); o.w = pack2(f[6], f[7]);
      *reinterpret_cast<uint4*>(&W1F[((size_t)(c * 49 + mt) * 64 + lane) * 8]) = o;
    }
  } else if (bid < 1137) {
    int i = bid - 113;
    const float* w = W1 + (size_t)i * INF;
    float acc[B];
#pragma unroll
    for (int b = 0; b < B; b++) acc[b] = 0.f;
    float wabs = 0.f;
    for (int k = t; k < INF; k += 256) {
      float wv = w[k];
      wabs += fabsf(wv);
#pragma unroll
      for (int b = 0; b < B; b++) acc[b] = fmaf(x[b * INF + k], wv, acc[b]);
    }
#pragma unroll
    for (int off = 32; off > 0; off >>= 1) {
#pragma unroll
      for (int b = 0; b < B; b++) acc[b] += __shfl_down(acc[b], off, 64);
      wabs += __shfl_down(wabs, off, 64);
    }
    int wave = t >> 6, lane = t & 63;
    if (lane == 0) {
#pragma unroll
      for (int b = 0; b < B; b++) red[wave][b] = acc[b];
      red[wave][B] = wabs;
    }
    __syncthreads();
    if (t < B) {
      float s = red[0][t] + red[1][t] + red[2][t] + red[3][t];
      float r = EPSV * (red[0][B] + red[1][B] + red[2][B] + red[3][B]);
      float nom = s + b1[i];
      float zl = nom - r, zu = nom + r;
      float d, l;
      if (zl >= 0.f)      { d = 1.f;            l = 0.f; }
      else if (zu > 0.f)  { d = zu / (zu - zl); l = zl;  }
      else                { d = 0.f;            l = 0.f; }
      d1B[(size_t)t * H1 + i] = d;
      t1B[(size_t)t * H1 + i] = d * l;
      dnB[(size_t)t * H1 + i] = d * nom;
    }
  } else {
    int zb = bid - 1137;
    for (int idx = t; idx < 8192; idx += 256) {
      int pos = zb * 8192 + idx;
      if (pos < 54272) Ezero[pos] = 0.f;
    }
  }
}

// ---------------------------------------------------------------------------
// K3: E[j,b] = eps * sum_k | sum_i W1[i,k] * (W2[j,i]*d1[b,i]) |
// v5 = r5 x r6: tall-A AND 3 waves/SIMD.  Per wave: 7 mt x 1 jt x 2 b.
// sp:MFMA = 4/mt -> mt=7 cuts scale-VALU per FLOP 1.6x vs r6's mt=5, while
// acc (56 AGPR) + dbuf loads (64 VGPR) ~ 140 unified keeps 3 waves/SIMD
// (r6 lesson: 3-wave overlap of MFMA+VALU pipes is what pays).
// 49 = 7x7: NO pad tiles; k-partitioning identical to r2 -> same numerics.
// grid (7, 16, 16) = 1792 blocks = 7/CU.
// ---------------------------------------------------------------------------
#define K3_LOAD(c, A, Bv) do {                                                  \
  Bv = *reinterpret_cast<const uint4*>(bBase + (size_t)(c) * 32768);            \
  _Pragma("unroll")                                                             \
  for (int mi = 0; mi < 7; mi++)                                                \
    A[mi] = *reinterpret_cast<const uint4*>(aBase + (size_t)(c) * 25088 + mi * 512); \
} while (0)

#define K3F_COMP(c, A, Bv, DsRow, accB) do {                                    \
  float4 dv0 = *reinterpret_cast<const float4*>(&DsRow[(c) * 32]);              \
  float4 dv1 = *reinterpret_cast<const float4*>(&DsRow[(c) * 32 + 4]);          \
  uint4 sb;                                                                     \
  sb.x = scale_pack(Bv.x, dv0.x, dv0.y);                                        \
  sb.y = scale_pack(Bv.y, dv0.z, dv0.w);                                        \
  sb.z = scale_pack(Bv.z, dv1.x, dv1.y);                                        \
  sb.w = scale_pack(Bv.w, dv1.z, dv1.w);                                        \
  short8 bfr = __builtin_bit_cast(short8, sb);                                  \
  _Pragma("unroll")                                                             \
  for (int mi = 0; mi < 7; mi++)                                                \
    accB[mi] = __builtin_amdgcn_mfma_f32_16x16x32_bf16(                         \
        __builtin_bit_cast(short8, A[mi]), bfr, accB[mi], 0, 0, 0);             \
} while (0)

__global__ __launch_bounds__(256, 3) void k3(
    const ushort* __restrict__ W1F, const ushort* __restrict__ W2F,
    const float* __restrict__ d1B, float* __restrict__ E)
{
  int b0 = blockIdx.z * 2;
  int t = threadIdx.x, w = t >> 6, lane = t & 63;
  int quad = lane >> 4, l15 = lane & 15;
  int mt0 = blockIdx.x * 7;
  int jt = blockIdx.y * 4 + w;

  __shared__ float Ds[2][H1];
  for (int idx = t; idx < 2 * H1; idx += 256)
    Ds[idx >> 10][idx & 1023] = d1B[(size_t)(b0 + (idx >> 10)) * H1 + (idx & 1023)];
  __syncthreads();

  const ushort* aBase = W1F + ((size_t)mt0 * 64 + lane) * 8;
  const ushort* bBase = W2F + ((size_t)jt * 64 + lane) * 8;
  const float* Ds0 = &Ds[0][quad * 8];
  const float* Ds1 = &Ds[1][quad * 8];

  floatx4 acc[2][7];
#pragma unroll
  for (int bb = 0; bb < 2; bb++)
#pragma unroll
    for (int mi = 0; mi < 7; mi++) acc[bb][mi] = (floatx4){0.f, 0.f, 0.f, 0.f};

  uint4 a0[7], a1[7], b0v, b1v;
  K3_LOAD(0, a0, b0v);
  K3_LOAD(1, a1, b1v);
  for (int c = 0; c < 30; c += 2) {
    K3F_COMP(c, a0, b0v, Ds0, acc[0]);
    K3F_COMP(c, a0, b0v, Ds1, acc[1]);
    K3_LOAD(c + 2, a0, b0v);
    K3F_COMP(c + 1, a1, b1v, Ds0, acc[0]);
    K3F_COMP(c + 1, a1, b1v, Ds1, acc[1]);
    if (c + 3 < 32) K3_LOAD(c + 3, a1, b1v);
  }
  K3F_COMP(30, a0, b0v, Ds0, acc[0]);
  K3F_COMP(30, a0, b0v, Ds1, acc[1]);
  K3F_COMP(31, a1, b1v, Ds0, acc[0]);
  K3F_COMP(31, a1, b1v, Ds1, acc[1]);

#pragma unroll
  for (int bb = 0; bb < 2; bb++) {
    float s = 0.f;
#pragma unroll
    for (int mi = 0; mi < 7; mi++)
#pragma unroll
      for (int r = 0; r < 4; r++) s += fabsf(acc[bb][mi][r]);
    s += __shfl_xor(s, 16, 64);
    s += __shfl_xor(s, 32, 64);
    if (lane < 16) {
      int j = jt * 16 + l15;
      atomicAdd(&E[(size_t)j * B + b0 + bb], EPSV * s);
    }
  }
}

// ---------------------------------------------------------------------------
// K245A: fused k2 matvecs + combine + nu2 build.  One block per j (= i2).
//  NOTE: B*NC = 320 > 256 threads -> phase2 is a strided loop.
// ---------------------------------------------------------------------------
__global__ __launch_bounds__(256) void k245a(
    const float* __restrict__ W2, const float* __restrict__ b2,
    const float* __restrict__ dnB, const float* __restrict__ t1B,
    const float* __restrict__ E, const float* __restrict__ W3,
    const int* __restrict__ y,
    float* __restrict__ nu2T, float* __restrict__ F2)
{
  int j = blockIdx.x;
  int t = threadIdx.x;
  int wave = t >> 6, lane = t & 63;
  int b0 = wave * 8;
  float aA[8] = {}, aCl[8] = {}, aCu[8] = {};
  const float* __restrict__ w2 = W2 + (size_t)j * H1;
  for (int i = lane; i < H1; i += 64) {
    float wv = w2[i];
    float wp = fmaxf(wv, 0.f), wn = fmaxf(-wv, 0.f);
#pragma unroll
    for (int r = 0; r < 8; r++) {
      float dv = dnB[(size_t)(b0 + r) * H1 + i];
      float tv = t1B[(size_t)(b0 + r) * H1 + i];
      aA[r]  = fmaf(wv, dv, aA[r]);
      aCl[r] = fmaf(wn, tv, aCl[r]);
      aCu[r] = fmaf(wp, tv, aCu[r]);
    }
  }
#pragma unroll
  for (int off = 32; off > 0; off >>= 1) {
#pragma unroll
    for (int r = 0; r < 8; r++) {
      aA[r]  += __shfl_down(aA[r],  off, 64);
      aCl[r] += __shfl_down(aCl[r], off, 64);
      aCu[r] += __shfl_down(aCu[r], off, 64);
    }
  }
  __shared__ float sA[B], sCl[B], sCu[B];
  __shared__ float sd2[B], st2[B], sdb[B], swy[B], sw3[NC];
  float bj = b2[j];
  if (lane == 0) {
#pragma unroll
    for (int r = 0; r < 8; r++) {
      sA [b0 + r] = aA[r] + bj;
      sCl[b0 + r] = aCl[r];
      sCu[b0 + r] = aCu[r];
    }
  }
  if (t >= 64 && t < 96)   swy[t - 64]  = W3[(size_t)y[t - 64] * H2 + j];
  if (t >= 128 && t < 138) sw3[t - 128] = W3[(size_t)(t - 128) * H2 + j];
  __syncthreads();
  if (t < B) {
    float a = sA[t], e = E[(size_t)j * B + t];
    float zl = a - e + sCl[t];
    float zu = a + e - sCu[t];
    float d, l;
    if (zl >= 0.f)      { d = 1.f;            l = 0.f; }
    else if (zu > 0.f)  { d = zu / (zu - zl); l = zl;  }
    else                { d = 0.f;            l = 0.f; }
    sd2[t] = d;
    st2[t] = d * l;
    sdb[t] = d * bj;
  }
  __syncthreads();
  for (int tt = t; tt < B * NC; tt += 256) {   // B*NC=320 > 256: strided!
    int b = tt / NC, jc = tt - b * NC;
    float cw = swy[b] - sw3[jc];
    float d2v = sd2[b];
    nu2T[((size_t)b * H2 + j) * 12 + jc] = cw * d2v;
    float val = cw * sdb[b] + fmaxf(-cw, 0.f) * st2[b];
    atomicAdd(&F2[((size_t)(j & 63) * B + b) * NC + jc], val);
  }
}

// ---------------------------------------------------------------------------
// K5b1: hpart[s][b][j][i1] = sum_{i2 in slice s (128)} nu2T[b][i2][j]*W2[i2,i1]
// 8 slices for parallelism; float2 i1 per thread.  grid (2, 32, 8), block 256.
// ---------------------------------------------------------------------------
__global__ __launch_bounds__(256) void k5b1(
    const float* __restrict__ W2, const float* __restrict__ nu2T,
    float* __restrict__ hpart)
{
  int t = threadIdx.x;
  int i1 = blockIdx.x * 512 + t * 2;
  int b = blockIdx.y, s = blockIdx.z;
  const float* __restrict__ nrowb = nu2T + ((size_t)b * H2 + s * 128) * 12;
  const float* __restrict__ w2b = W2 + (size_t)s * 128 * H1 + i1;
  float h0[NC] = {}, h1[NC] = {};
  for (int i2 = 0; i2 < 128; i2++) {
    float2 wv = *reinterpret_cast<const float2*>(&w2b[(size_t)i2 * H1]);
    const float* __restrict__ nrow = nrowb + i2 * 12;
#pragma unroll
    for (int j = 0; j < NC; j++) {
      h0[j] = fmaf(nrow[j], wv.x, h0[j]);
      h1[j] = fmaf(nrow[j], wv.y, h1[j]);
    }
  }
#pragma unroll
  for (int j = 0; j < NC; j++) {
    float2 o; o.x = h0[j]; o.y = h1[j];
    *reinterpret_cast<float2*>(&hpart[(((size_t)s * B + b) * NC + j) * H1 + i1]) = o;
  }
}

// ---------------------------------------------------------------------------
// K5b2: h = sum_s hpart; nu1fT[b][i1][j] = h*d1; F += h*dn + relu(-h)*t1m
// ---------------------------------------------------------------------------
__global__ __launch_bounds__(256) void k5b2(
    const float* __restrict__ hpart,
    const float* __restrict__ d1B, const float* __restrict__ t1B,
    const float* __restrict__ dnB,
    float* __restrict__ nu1fT, float* __restrict__ F)
{
  int t = threadIdx.x;
  int i1 = blockIdx.x * 256 + t;
  int b = blockIdx.y;
  float d1v = d1B[(size_t)b * H1 + i1];
  float t1v = t1B[(size_t)b * H1 + i1];
  float dnv = dnB[(size_t)b * H1 + i1];
  float sn[NC], c1[NC];
#pragma unroll
  for (int j = 0; j < NC; j++) {
    float hv = 0.f;
#pragma unroll
    for (int s = 0; s < 8; s++)
      hv += hpart[(((size_t)s * B + b) * NC + j) * H1 + i1];
    nu1fT[((size_t)b * H1 + i1) * 12 + j] = hv * d1v;
    sn[j] = hv * dnv;
    c1[j] = fmaxf(-hv, 0.f) * t1v;
  }
#pragma unroll
  for (int off = 32; off > 0; off >>= 1) {
#pragma unroll
    for (int j = 0; j < NC; j++) {
      sn[j] += __shfl_down(sn[j], off, 64);
      c1[j] += __shfl_down(c1[j], off, 64);
    }
  }
  __shared__ float red[4][2 * NC];
  int wave = t >> 6, lane = t & 63;
  if (lane == 0) {
#pragma unroll
    for (int j = 0; j < NC; j++) { red[wave][j] = sn[j]; red[wave][NC + j] = c1[j]; }
  }
  __syncthreads();
  if (t < NC) {
    float s = 0.f;
    for (int w = 0; w < 4; w++) s += red[w][t] + red[w][NC + t];
    atomicAdd(&F[b * NC + t], s);
  }
}

// ---------------------------------------------------------------------------
// K5c1: ppart[s][b][j][k] = sum_{i1 in slice s (128)} nu1fT[b][i1][j]*W1[i1,k]
// grid (7, 32, 8), block 128 (t<112 active).
// ---------------------------------------------------------------------------
__global__ __launch_bounds__(128) void k5c1(
    const float* __restrict__ W1, const float* __restrict__ nu1fT,
    float* __restrict__ ppart)
{
  int t = threadIdx.x;
  bool valid = (t < 112);
  int k = blockIdx.x * 112 + (valid ? t : 0);
  int b = blockIdx.y, s = blockIdx.z;
  const float* __restrict__ nrowb = nu1fT + ((size_t)b * H1 + s * 128) * 12;
  const float* __restrict__ w1b = W1 + (size_t)s * 128 * INF + k;
  float acc[NC] = {};
  for (int i1 = 0; i1 < 128; i1++) {
    float w1v = w1b[(size_t)i1 * INF];
    const float* __restrict__ nrow = nrowb + i1 * 12;
#pragma unroll
    for (int j = 0; j < NC; j++) acc[j] = fmaf(nrow[j], w1v, acc[j]);
  }
  if (valid) {
#pragma unroll
    for (int j = 0; j < NC; j++)
      ppart[(((size_t)s * B + b) * NC + j) * INF + k] = acc[j];
  }
}

// ---------------------------------------------------------------------------
// K5c2 + out: per b: Ef[j] = eps*sum_k |sum_s ppart|;
// out = eps*Ef - (F + sum_slots F2 + b3[yb]-b3[jc]).
// ---------------------------------------------------------------------------
__global__ __launch_bounds__(256) void k5c2_out(
    const float* __restrict__ ppart, const float* __restrict__ F,
    const float* __restrict__ F2, const float* __restrict__ b3,
    const int* __restrict__ y, float* __restrict__ out)
{
  int b = blockIdx.x;
  int t = threadIdx.x;
  float e[NC] = {};
  for (int k = t; k < INF; k += 256) {
#pragma unroll
    for (int j = 0; j < NC; j++) {
      float v = 0.f;
#pragma unroll
      for (int s = 0; s < 8; s++)
        v += ppart[(((size_t)s * B + b) * NC + j) * INF + k];
      e[j] += fabsf(v);
    }
  }
#pragma unroll
  for (int off = 32; off > 0; off >>= 1) {
#pragma unroll
    for (int j = 0; j < NC; j++) e[j] += __shfl_down(e[j], off, 64);
  }
  __shared__ float red[4][NC];
  int wave = t >> 6, lane = t & 63;
  if (lane == 0) {
#pragma unroll
    for (int j = 0; j < NC; j++) red[wave][j] = e[j];
  }
  __syncthreads();
  if (t < NC) {
    float ef = 0.f;
    for (int w = 0; w < 4; w++) ef += red[w][t];
    float s = F[b * NC + t];
    for (int slot = 0; slot < 64; slot++)
      s += F2[((size_t)slot * B + b) * NC + t];
    int yb = y[b];
    s += b3[yb] - b3[t];
    out[b * NC + t] = EPSV * ef - s;
  }
}

// ---------------------------------------------------------------------------
extern "C" void kernel_launch(void* const* d_in, const int* in_sizes, int n_in,
                              void* d_out, int out_size, void* d_ws, size_t ws_size,
                              hipStream_t stream) {
  const float* x  = (const float*)d_in[0];
  const int*   y  = (const int*)  d_in[1];
  const float* W1 = (const float*)d_in[2];
  const float* b1 = (const float*)d_in[3];
  const float* W2 = (const float*)d_in[4];
  const float* b2 = (const float*)d_in[5];
  const float* W3 = (const float*)d_in[6];
  const float* b3 = (const float*)d_in[7];
  float* out = (float*)d_out;
  float* ws  = (float*)d_ws;

  // ---- workspace layout (floats), with lifetime overlays ----
  float* d1B  = ws;
  float* t1B  = ws + 32768;
  float* dnB  = ws + 65536;
  float* E    = ws + 196608;    // 32768 (zeroed in k_pre)
  float* F    = ws + 229376;    // 320, pad to 1024 (zeroed)
  float* F2   = ws + 230400;    // 64*32*10 = 20480 (zeroed; zero-range 54272 from E)
  float* nu2T = ws + 328704;    // 393216, k245a -> k5b1 (ends 721920)
  ushort* W2F = (ushort*)(ws + 721920);    // 1048576 us (ends 1246208)
  ushort* W1F = (ushort*)(ws + 1246208);   // 802816 us (ends 1647616)
  // overlays (disjoint lifetimes):
  float* nu1fT = ws + 328704;   // over nu2T (k5b2 -> k5c1)
  float* hpart = ws + 721920;   // 8*32*10*1024 = 2621440 f over W2F/W1F (k5b1 -> k5b2)
  float* ppart = ws + 721920;   // 8*32*10*784 = 2007040 f, same region (k5c1 -> k5c2)

  k_pre<<<1144, 256, 0, stream>>>(x, W1, b1, W2, W1F, W2F, d1B, t1B, dnB, E);
  k3<<<dim3(7, 16, 16), 256, 0, stream>>>(W1F, W2F, d1B, E);
  k245a<<<H2, 256, 0, stream>>>(W2, b2, dnB, t1B, E, W3, y, nu2T, F2);
  k5b1<<<dim3(2, B, 8), 256, 0, stream>>>(W2, nu2T, hpart);
  k5b2<<<dim3(4, B), 256, 0, stream>>>(hpart, d1B, t1B, dnB, nu1fT, F);
  k5c1<<<dim3(7, B, 8), 128, 0, stream>>>(W1, nu1fT, ppart);
  k5c2_out<<<B, 256, 0, stream>>>(ppart, F, F2, b3, y, out);
}

// Round 8
// 216.556 us; speedup vs baseline: 1.0309x; 1.0309x over previous
//
#include <hip/hip_runtime.h>
#include <math.h>

#define B    32
#define INF  784
#define H1   1024
#define H2   1024
#define NC   10
#define EPSV 0.1f

typedef __attribute__((ext_vector_type(8))) short short8;
typedef __attribute__((ext_vector_type(4))) float floatx4;

__device__ inline ushort bf16_rne(float f) {
  uint u = __builtin_bit_cast(uint, f);
  u += 0x7FFFu + ((u >> 16) & 1u);
  return (ushort)(u >> 16);
}
__device__ inline uint pack2(float a, float b) {
  return (uint)bf16_rne(a) | ((uint)bf16_rne(b) << 16);
}
// scale a packed pair of bf16 (in dword u) by d0,d1 and repack (round-half-up,
// matches r4 numerics — do NOT change rounding)
__device__ inline uint scale_pack(uint u, float d0, float d1v) {
  float f0 = __builtin_bit_cast(float, u << 16) * d0;
  float f1 = __builtin_bit_cast(float, u & 0xFFFF0000u) * d1v;
  uint r0 = __builtin_bit_cast(uint, f0) + 0x8000u;
  uint r1 = __builtin_bit_cast(uint, f1) + 0x8000u;
  return __builtin_amdgcn_perm(r1, r0, 0x07060302u);
}

// async global->LDS, 16B per lane.  LDS dest is wave-uniform base (+lane*16 by HW).
typedef __attribute__((address_space(1))) const unsigned int g_as1;
typedef __attribute__((address_space(3))) unsigned int l_as3;
__device__ __forceinline__ void gll16(const void* g, void* l) {
  __builtin_amdgcn_global_load_lds((g_as1*)g, (l_as3*)l, 16, 0, 0);
}

// ---------------------------------------------------------------------------
// K_PRE: merged preprocessing + zero-init.  (r5 structure, W1F stride 52)
//  [0,64):      W2F fragment pack
//  [64,116):    W1F fragment pack, stride 52 (mt 49..51 = zero pad tiles so
//               k3 can use 13 mt-tiles/block x 4 blocks = 52)
//  [116,1140):  layer-1 row i = bid-116
//  [1140,1147): zero E/F/F2 region (54272 floats from E base)
// ---------------------------------------------------------------------------
__global__ __launch_bounds__(256) void k_pre(
    const float* __restrict__ x, const float* __restrict__ W1,
    const float* __restrict__ b1, const float* __restrict__ W2,
    ushort* __restrict__ W1F, ushort* __restrict__ W2F,
    float* __restrict__ d1B, float* __restrict__ t1B, float* __restrict__ dnB,
    float* __restrict__ Ezero)
{
  __shared__ float red[4][B + 1];
  __shared__ float Ts[4][32][17];
  int bid = blockIdx.x;
  int t = threadIdx.x;
  if (bid < 64) {
    int jt = bid;
    int lane = t & 63, c0 = t >> 6;
    int l15 = lane & 15, quad = lane >> 4;
    for (int c = c0; c < 32; c += 4) {
      const float* src = &W2[(size_t)(jt * 16 + l15) * H1 + c * 32 + quad * 8];
      float4 v0 = *reinterpret_cast<const float4*>(src);
      float4 v1 = *reinterpret_cast<const float4*>(src + 4);
      uint4 o;
      o.x = pack2(v0.x, v0.y); o.y = pack2(v0.z, v0.w);
      o.z = pack2(v1.x, v1.y); o.w = pack2(v1.z, v1.w);
      *reinterpret_cast<uint4*>(&W2F[((size_t)(c * 64 + jt) * 64 + lane) * 8]) = o;
    }
  } else if (bid < 116) {
    int mt = bid - 64;                 // 0..51
    int w = t >> 6, lane = t & 63;
    int l15 = lane & 15, quad = lane >> 4;
    if (mt >= 49) {
      // zero-pad tiles: W1 columns p >= 784 are zero -> zero fragments
      uint4 z; z.x = 0; z.y = 0; z.z = 0; z.w = 0;
      for (int cg = 0; cg < 8; cg++) {
        int c = cg * 4 + w;
        *reinterpret_cast<uint4*>(&W1F[((size_t)(c * 52 + mt) * 64 + lane) * 8]) = z;
      }
    } else {
      int col0 = mt * 16;
      for (int cg = 0; cg < 8; cg++) {
        int c = cg * 4 + w;
#pragma unroll
        for (int p = 0; p < 8; p++) {
          int r = p * 4 + (lane >> 4);
          Ts[w][r][lane & 15] = W1[(size_t)(c * 32 + r) * INF + col0 + (lane & 15)];
        }
        float f[8];
#pragma unroll
        for (int e = 0; e < 8; e++) f[e] = Ts[w][quad * 8 + e][l15];
        uint4 o;
        o.x = pack2(f[0], f[1]); o.y = pack2(f[2], f[3]);
        o.z = pack2(f[4], f[5]); o.w = pack2(f[6], f[7]);
        *reinterpret_cast<uint4*>(&W1F[((size_t)(c * 52 + mt) * 64 + lane) * 8]) = o;
      }
    }
  } else if (bid < 1140) {
    int i = bid - 116;
    const float* w = W1 + (size_t)i * INF;
    float acc[B];
#pragma unroll
    for (int b = 0; b < B; b++) acc[b] = 0.f;
    float wabs = 0.f;
    for (int k = t; k < INF; k += 256) {
      float wv = w[k];
      wabs += fabsf(wv);
#pragma unroll
      for (int b = 0; b < B; b++) acc[b] = fmaf(x[b * INF + k], wv, acc[b]);
    }
#pragma unroll
    for (int off = 32; off > 0; off >>= 1) {
#pragma unroll
      for (int b = 0; b < B; b++) acc[b] += __shfl_down(acc[b], off, 64);
      wabs += __shfl_down(wabs, off, 64);
    }
    int wave = t >> 6, lane = t & 63;
    if (lane == 0) {
#pragma unroll
      for (int b = 0; b < B; b++) red[wave][b] = acc[b];
      red[wave][B] = wabs;
    }
    __syncthreads();
    if (t < B) {
      float s = red[0][t] + red[1][t] + red[2][t] + red[3][t];
      float r = EPSV * (red[0][B] + red[1][B] + red[2][B] + red[3][B]);
      float nom = s + b1[i];
      float zl = nom - r, zu = nom + r;
      float d, l;
      if (zl >= 0.f)      { d = 1.f;            l = 0.f; }
      else if (zu > 0.f)  { d = zu / (zu - zl); l = zl;  }
      else                { d = 0.f;            l = 0.f; }
      d1B[(size_t)t * H1 + i] = d;
      t1B[(size_t)t * H1 + i] = d * l;
      dnB[(size_t)t * H1 + i] = d * nom;
    }
  } else {
    int zb = bid - 1140;
    for (int idx = t; idx < 8192; idx += 256) {
      int pos = zb * 8192 + idx;
      if (pos < 54272) Ezero[pos] = 0.f;
    }
  }
}

// ---------------------------------------------------------------------------
// K3: E[j,b] = eps * sum_k | sum_i W1[i,k] * (W2[j,i]*d1[b,i]) |
// v6: LDS-staged A (m97 pattern).  nx=4 k-groups (mt=13) cuts scale-VALU
// total 2.5x vs r6, WITHOUT the r5 register wall: A-fragments are staged via
// global_load_lds (no VGPR dbuf), shared by all 4 waves (same mt-range,
// different jt).  acc 104 AGPR + B dbuf 8 + addr ~ 140 regs -> 3 waves/SIMD.
// LDS: Ds 8K + A dbuf 2x13K = 34.8K -> 3 blocks/CU.
// Per c-step: coop-issue 13 glds for c+1 | scale 8 dw | 13 ds_read_b128 |
// 26 MFMA | barrier (drains own glds -> cross-wave visibility).
// grid (4, 16, 16).  Pads (tiles 49-51) contribute |0| = 0.
// ---------------------------------------------------------------------------
#define K3_ISSUE(c, buf) do {                                                   \
  for (int mi = w; mi < 13; mi += 4)                                            \
    gll16(W1F + (((size_t)(c) * 52 + mtBase + mi) * 64 + lane) * 8,             \
          &Abuf[buf][mi * 64]);                                                 \
} while (0)

#define K3_SCALE(bv, DsRow, cc, bfr) do {                                       \
  float4 dv0 = *reinterpret_cast<const float4*>(&DsRow[(cc) * 32]);             \
  float4 dv1 = *reinterpret_cast<const float4*>(&DsRow[(cc) * 32 + 4]);         \
  uint4 sb;                                                                     \
  sb.x = scale_pack(bv.x, dv0.x, dv0.y);                                        \
  sb.y = scale_pack(bv.y, dv0.z, dv0.w);                                        \
  sb.z = scale_pack(bv.z, dv1.x, dv1.y);                                        \
  sb.w = scale_pack(bv.w, dv1.z, dv1.w);                                        \
  bfr = __builtin_bit_cast(short8, sb);                                         \
} while (0)

#define K3_MFMA(buf, bf0, bf1) do {                                             \
  _Pragma("unroll")                                                             \
  for (int mi = 0; mi < 13; mi++) {                                             \
    short8 af = *reinterpret_cast<const short8*>(&Abuf[buf][mi * 64 + lane]);   \
    acc[0][mi] = __builtin_amdgcn_mfma_f32_16x16x32_bf16(af, bf0, acc[0][mi], 0, 0, 0); \
    acc[1][mi] = __builtin_amdgcn_mfma_f32_16x16x32_bf16(af, bf1, acc[1][mi], 0, 0, 0); \
  }                                                                             \
} while (0)

__global__ __launch_bounds__(256, 3) void k3(
    const ushort* __restrict__ W1F, const ushort* __restrict__ W2F,
    const float* __restrict__ d1B, float* __restrict__ E)
{
  int b0 = blockIdx.z * 2;
  int t = threadIdx.x, w = t >> 6, lane = t & 63;
  int quad = lane >> 4, l15 = lane & 15;
  int jt = blockIdx.y * 4 + w;
  int mtBase = blockIdx.x * 13;

  __shared__ float Ds[2][H1];
  __shared__ uint4 Abuf[2][13 * 64];   // 2 x 13 KB

  for (int idx = t; idx < 2 * H1; idx += 256)
    Ds[idx >> 10][idx & 1023] = d1B[(size_t)(b0 + (idx >> 10)) * H1 + (idx & 1023)];

  const ushort* bBase = W2F + ((size_t)jt * 64 + lane) * 8;
  const float* Ds0 = &Ds[0][quad * 8];
  const float* Ds1 = &Ds[1][quad * 8];

  floatx4 acc[2][13];
#pragma unroll
  for (int bb = 0; bb < 2; bb++)
#pragma unroll
    for (int mi = 0; mi < 13; mi++) acc[bb][mi] = (floatx4){0.f, 0.f, 0.f, 0.f};

  K3_ISSUE(0, 0);
  uint4 bv0 = *reinterpret_cast<const uint4*>(bBase);
  uint4 bv1 = *reinterpret_cast<const uint4*>(bBase + 32768);
  __syncthreads();   // Ds ready + Abuf[0] landed (vmcnt drain)

  for (int c = 0; c < 32; c += 2) {
    // ---- phase A: compute c from Abuf[0] ----
    if (c + 1 < 32) K3_ISSUE(c + 1, 1);
    {
      short8 bf0, bf1;
      K3_SCALE(bv0, Ds0, c, bf0);
      K3_SCALE(bv0, Ds1, c, bf1);
      if (c + 2 < 32) bv0 = *reinterpret_cast<const uint4*>(bBase + (size_t)(c + 2) * 32768);
      K3_MFMA(0, bf0, bf1);
    }
    __syncthreads();   // Abuf[0] free; Abuf[1] (c+1) landed
    // ---- phase B: compute c+1 from Abuf[1] ----
    if (c + 2 < 32) K3_ISSUE(c + 2, 0);
    {
      short8 bf0, bf1;
      K3_SCALE(bv1, Ds0, c + 1, bf0);
      K3_SCALE(bv1, Ds1, c + 1, bf1);
      if (c + 3 < 32) bv1 = *reinterpret_cast<const uint4*>(bBase + (size_t)(c + 3) * 32768);
      K3_MFMA(1, bf0, bf1);
    }
    __syncthreads();   // Abuf[1] free; Abuf[0] (c+2) landed
  }

#pragma unroll
  for (int bb = 0; bb < 2; bb++) {
    float s = 0.f;
#pragma unroll
    for (int mi = 0; mi < 13; mi++)
#pragma unroll
      for (int r = 0; r < 4; r++) s += fabsf(acc[bb][mi][r]);
    s += __shfl_xor(s, 16, 64);
    s += __shfl_xor(s, 32, 64);
    if (lane < 16) {
      int j = jt * 16 + l15;
      atomicAdd(&E[(size_t)j * B + b0 + bb], EPSV * s);
    }
  }
}

// ---------------------------------------------------------------------------
// K245A: fused k2 matvecs + combine + nu2 build.  One block per j (= i2).
//  NOTE: B*NC = 320 > 256 threads -> phase2 is a strided loop.
// ---------------------------------------------------------------------------
__global__ __launch_bounds__(256) void k245a(
    const float* __restrict__ W2, const float* __restrict__ b2,
    const float* __restrict__ dnB, const float* __restrict__ t1B,
    const float* __restrict__ E, const float* __restrict__ W3,
    const int* __restrict__ y,
    float* __restrict__ nu2T, float* __restrict__ F2)
{
  int j = blockIdx.x;
  int t = threadIdx.x;
  int wave = t >> 6, lane = t & 63;
  int b0 = wave * 8;
  float aA[8] = {}, aCl[8] = {}, aCu[8] = {};
  const float* __restrict__ w2 = W2 + (size_t)j * H1;
  for (int i = lane; i < H1; i += 64) {
    float wv = w2[i];
    float wp = fmaxf(wv, 0.f), wn = fmaxf(-wv, 0.f);
#pragma unroll
    for (int r = 0; r < 8; r++) {
      float dv = dnB[(size_t)(b0 + r) * H1 + i];
      float tv = t1B[(size_t)(b0 + r) * H1 + i];
      aA[r]  = fmaf(wv, dv, aA[r]);
      aCl[r] = fmaf(wn, tv, aCl[r]);
      aCu[r] = fmaf(wp, tv, aCu[r]);
    }
  }
#pragma unroll
  for (int off = 32; off > 0; off >>= 1) {
#pragma unroll
    for (int r = 0; r < 8; r++) {
      aA[r]  += __shfl_down(aA[r],  off, 64);
      aCl[r] += __shfl_down(aCl[r], off, 64);
      aCu[r] += __shfl_down(aCu[r], off, 64);
    }
  }
  __shared__ float sA[B], sCl[B], sCu[B];
  __shared__ float sd2[B], st2[B], sdb[B], swy[B], sw3[NC];
  float bj = b2[j];
  if (lane == 0) {
#pragma unroll
    for (int r = 0; r < 8; r++) {
      sA [b0 + r] = aA[r] + bj;
      sCl[b0 + r] = aCl[r];
      sCu[b0 + r] = aCu[r];
    }
  }
  if (t >= 64 && t < 96)   swy[t - 64]  = W3[(size_t)y[t - 64] * H2 + j];
  if (t >= 128 && t < 138) sw3[t - 128] = W3[(size_t)(t - 128) * H2 + j];
  __syncthreads();
  if (t < B) {
    float a = sA[t], e = E[(size_t)j * B + t];
    float zl = a - e + sCl[t];
    float zu = a + e - sCu[t];
    float d, l;
    if (zl >= 0.f)      { d = 1.f;            l = 0.f; }
    else if (zu > 0.f)  { d = zu / (zu - zl); l = zl;  }
    else                { d = 0.f;            l = 0.f; }
    sd2[t] = d;
    st2[t] = d * l;
    sdb[t] = d * bj;
  }
  __syncthreads();
  for (int tt = t; tt < B * NC; tt += 256) {   // B*NC=320 > 256: strided!
    int b = tt / NC, jc = tt - b * NC;
    float cw = swy[b] - sw3[jc];
    float d2v = sd2[b];
    nu2T[((size_t)b * H2 + j) * 12 + jc] = cw * d2v;
    float val = cw * sdb[b] + fmaxf(-cw, 0.f) * st2[b];
    atomicAdd(&F2[((size_t)(j & 63) * B + b) * NC + jc], val);
  }
}

// ---------------------------------------------------------------------------
// K5b1: hpart[s][b][j][i1] = sum_{i2 in slice s (128)} nu2T[b][i2][j]*W2[i2,i1]
// 8 slices for parallelism; float2 i1 per thread.  grid (2, 32, 8), block 256.
// ---------------------------------------------------------------------------
__global__ __launch_bounds__(256) void k5b1(
    const float* __restrict__ W2, const float* __restrict__ nu2T,
    float* __restrict__ hpart)
{
  int t = threadIdx.x;
  int i1 = blockIdx.x * 512 + t * 2;
  int b = blockIdx.y, s = blockIdx.z;
  const float* __restrict__ nrowb = nu2T + ((size_t)b * H2 + s * 128) * 12;
  const float* __restrict__ w2b = W2 + (size_t)s * 128 * H1 + i1;
  float h0[NC] = {}, h1[NC] = {};
  for (int i2 = 0; i2 < 128; i2++) {
    float2 wv = *reinterpret_cast<const float2*>(&w2b[(size_t)i2 * H1]);
    const float* __restrict__ nrow = nrowb + i2 * 12;
#pragma unroll
    for (int j = 0; j < NC; j++) {
      h0[j] = fmaf(nrow[j], wv.x, h0[j]);
      h1[j] = fmaf(nrow[j], wv.y, h1[j]);
    }
  }
#pragma unroll
  for (int j = 0; j < NC; j++) {
    float2 o; o.x = h0[j]; o.y = h1[j];
    *reinterpret_cast<float2*>(&hpart[(((size_t)s * B + b) * NC + j) * H1 + i1]) = o;
  }
}

// ---------------------------------------------------------------------------
// K5b2: h = sum_s hpart; nu1fT[b][i1][j] = h*d1; F += h*dn + relu(-h)*t1m
// ---------------------------------------------------------------------------
__global__ __launch_bounds__(256) void k5b2(
    const float* __restrict__ hpart,
    const float* __restrict__ d1B, const float* __restrict__ t1B,
    const float* __restrict__ dnB,
    float* __restrict__ nu1fT, float* __restrict__ F)
{
  int t = threadIdx.x;
  int i1 = blockIdx.x * 256 + t;
  int b = blockIdx.y;
  float d1v = d1B[(size_t)b * H1 + i1];
  float t1v = t1B[(size_t)b * H1 + i1];
  float dnv = dnB[(size_t)b * H1 + i1];
  float sn[NC], c1[NC];
#pragma unroll
  for (int j = 0; j < NC; j++) {
    float hv = 0.f;
#pragma unroll
    for (int s = 0; s < 8; s++)
      hv += hpart[(((size_t)s * B + b) * NC + j) * H1 + i1];
    nu1fT[((size_t)b * H1 + i1) * 12 + j] = hv * d1v;
    sn[j] = hv * dnv;
    c1[j] = fmaxf(-hv, 0.f) * t1v;
  }
#pragma unroll
  for (int off = 32; off > 0; off >>= 1) {
#pragma unroll
    for (int j = 0; j < NC; j++) {
      sn[j] += __shfl_down(sn[j], off, 64);
      c1[j] += __shfl_down(c1[j], off, 64);
    }
  }
  __shared__ float red[4][2 * NC];
  int wave = t >> 6, lane = t & 63;
  if (lane == 0) {
#pragma unroll
    for (int j = 0; j < NC; j++) { red[wave][j] = sn[j]; red[wave][NC + j] = c1[j]; }
  }
  __syncthreads();
  if (t < NC) {
    float s = 0.f;
    for (int w = 0; w < 4; w++) s += red[w][t] + red[w][NC + t];
    atomicAdd(&F[b * NC + t], s);
  }
}

// ---------------------------------------------------------------------------
// K5c1: ppart[s][b][j][k] = sum_{i1 in slice s (128)} nu1fT[b][i1][j]*W1[i1,k]
// grid (7, 32, 8), block 128 (t<112 active).
// ---------------------------------------------------------------------------
__global__ __launch_bounds__(128) void k5c1(
    const float* __restrict__ W1, const float* __restrict__ nu1fT,
    float* __restrict__ ppart)
{
  int t = threadIdx.x;
  bool valid = (t < 112);
  int k = blockIdx.x * 112 + (valid ? t : 0);
  int b = blockIdx.y, s = blockIdx.z;
  const float* __restrict__ nrowb = nu1fT + ((size_t)b * H1 + s * 128) * 12;
  const float* __restrict__ w1b = W1 + (size_t)s * 128 * INF + k;
  float acc[NC] = {};
  for (int i1 = 0; i1 < 128; i1++) {
    float w1v = w1b[(size_t)i1 * INF];
    const float* __restrict__ nrow = nrowb + i1 * 12;
#pragma unroll
    for (int j = 0; j < NC; j++) acc[j] = fmaf(nrow[j], w1v, acc[j]);
  }
  if (valid) {
#pragma unroll
    for (int j = 0; j < NC; j++)
      ppart[(((size_t)s * B + b) * NC + j) * INF + k] = acc[j];
  }
}

// ---------------------------------------------------------------------------
// K5c2 + out: per b: Ef[j] = eps*sum_k |sum_s ppart|;
// out = eps*Ef - (F + sum_slots F2 + b3[yb]-b3[jc]).
// ---------------------------------------------------------------------------
__global__ __launch_bounds__(256) void k5c2_out(
    const float* __restrict__ ppart, const float* __restrict__ F,
    const float* __restrict__ F2, const float* __restrict__ b3,
    const int* __restrict__ y, float* __restrict__ out)
{
  int b = blockIdx.x;
  int t = threadIdx.x;
  float e[NC] = {};
  for (int k = t; k < INF; k += 256) {
#pragma unroll
    for (int j = 0; j < NC; j++) {
      float v = 0.f;
#pragma unroll
      for (int s = 0; s < 8; s++)
        v += ppart[(((size_t)s * B + b) * NC + j) * INF + k];
      e[j] += fabsf(v);
    }
  }
#pragma unroll
  for (int off = 32; off > 0; off >>= 1) {
#pragma unroll
    for (int j = 0; j < NC; j++) e[j] += __shfl_down(e[j], off, 64);
  }
  __shared__ float red[4][NC];
  int wave = t >> 6, lane = t & 63;
  if (lane == 0) {
#pragma unroll
    for (int j = 0; j < NC; j++) red[wave][j] = e[j];
  }
  __syncthreads();
  if (t < NC) {
    float ef = 0.f;
    for (int w = 0; w < 4; w++) ef += red[w][t];
    float s = F[b * NC + t];
    for (int slot = 0; slot < 64; slot++)
      s += F2[((size_t)slot * B + b) * NC + t];
    int yb = y[b];
    s += b3[yb] - b3[t];
    out[b * NC + t] = EPSV * ef - s;
  }
}

// ---------------------------------------------------------------------------
extern "C" void kernel_launch(void* const* d_in, const int* in_sizes, int n_in,
                              void* d_out, int out_size, void* d_ws, size_t ws_size,
                              hipStream_t stream) {
  const float* x  = (const float*)d_in[0];
  const int*   y  = (const int*)  d_in[1];
  const float* W1 = (const float*)d_in[2];
  const float* b1 = (const float*)d_in[3];
  const float* W2 = (const float*)d_in[4];
  const float* b2 = (const float*)d_in[5];
  const float* W3 = (const float*)d_in[6];
  const float* b3 = (const float*)d_in[7];
  float* out = (float*)d_out;
  float* ws  = (float*)d_ws;

  // ---- workspace layout (floats), with lifetime overlays ----
  float* d1B  = ws;
  float* t1B  = ws + 32768;
  float* dnB  = ws + 65536;
  float* E    = ws + 196608;    // 32768 (zeroed in k_pre)
  float* F    = ws + 229376;    // 320, pad to 1024 (zeroed)
  float* F2   = ws + 230400;    // 64*32*10 = 20480 (zeroed; zero-range 54272 from E)
  float* nu2T = ws + 328704;    // 393216, k245a -> k5b1 (ends 721920)
  ushort* W2F = (ushort*)(ws + 721920);    // 1048576 us (ends 1246208)
  ushort* W1F = (ushort*)(ws + 1246208);   // 32*52*512 = 851968 us (ends 1672192)
  // overlays (disjoint lifetimes):
  float* nu1fT = ws + 328704;   // over nu2T (k5b2 -> k5c1)
  float* hpart = ws + 721920;   // 8*32*10*1024 = 2621440 f over W2F/W1F (k5b1 -> k5b2)
  float* ppart = ws + 721920;   // 8*32*10*784 = 2007040 f, same region (k5c1 -> k5c2)

  k_pre<<<1147, 256, 0, stream>>>(x, W1, b1, W2, W1F, W2F, d1B, t1B, dnB, E);
  k3<<<dim3(4, 16, 16), 256, 0, stream>>>(W1F, W2F, d1B, E);
  k245a<<<H2, 256, 0, stream>>>(W2, b2, dnB, t1B, E, W3, y, nu2T, F2);
  k5b1<<<dim3(2, B, 8), 256, 0, stream>>>(W2, nu2T, hpart);
  k5b2<<<dim3(4, B), 256, 0, stream>>>(hpart, d1B, t1B, dnB, nu1fT, F);
  k5c1<<<dim3(7, B, 8), 128, 0, stream>>>(W1, nu1fT, ppart);
  k5c2_out<<<B, 256, 0, stream>>>(ppart, F, F2, b3, y, out);
}

// Round 9
// 209.401 us; speedup vs baseline: 1.0661x; 1.0342x over previous
//
#include <hip/hip_runtime.h>
#include <math.h>

#define B    32
#define INF  784
#define H1   1024
#define H2   1024
#define NC   10
#define EPSV 0.1f

typedef __attribute__((ext_vector_type(8))) short short8;
typedef __attribute__((ext_vector_type(4))) float floatx4;

__device__ inline ushort bf16_rne(float f) {
  uint u = __builtin_bit_cast(uint, f);
  u += 0x7FFFu + ((u >> 16) & 1u);
  return (ushort)(u >> 16);
}
__device__ inline uint pack2(float a, float b) {
  return (uint)bf16_rne(a) | ((uint)bf16_rne(b) << 16);
}
// scale a packed pair of bf16 (in dword u) by d0,d1 and repack (round-half-up,
// matches r4 numerics — do NOT change rounding)
__device__ inline uint scale_pack(uint u, float d0, float d1v) {
  float f0 = __builtin_bit_cast(float, u << 16) * d0;
  float f1 = __builtin_bit_cast(float, u & 0xFFFF0000u) * d1v;
  uint r0 = __builtin_bit_cast(uint, f0) + 0x8000u;
  uint r1 = __builtin_bit_cast(uint, f1) + 0x8000u;
  return __builtin_amdgcn_perm(r1, r0, 0x07060302u);
}

// ---------------------------------------------------------------------------
// K_PRE: merged preprocessing + zero-init.  (r2/r6 structure, W1F stride 49)
//  [0,64):     W2F fragment pack
//  [64,113):   W1F fragment pack via LDS transpose (coalesced reads)
//  [113,1137): layer-1 row i = bid-113
//  [1137,1144): zero E/F/F2/EfB region (55296 floats from E base)
// ---------------------------------------------------------------------------
__global__ __launch_bounds__(256) void k_pre(
    const float* __restrict__ x, const float* __restrict__ W1,
    const float* __restrict__ b1, const float* __restrict__ W2,
    ushort* __restrict__ W1F, ushort* __restrict__ W2F,
    float* __restrict__ d1B, float* __restrict__ t1B, float* __restrict__ dnB,
    float* __restrict__ Ezero)
{
  __shared__ float red[4][B + 1];
  __shared__ float Ts[4][32][17];
  int bid = blockIdx.x;
  int t = threadIdx.x;
  if (bid < 64) {
    int jt = bid;
    int lane = t & 63, c0 = t >> 6;
    int l15 = lane & 15, quad = lane >> 4;
    for (int c = c0; c < 32; c += 4) {
      const float* src = &W2[(size_t)(jt * 16 + l15) * H1 + c * 32 + quad * 8];
      float4 v0 = *reinterpret_cast<const float4*>(src);
      float4 v1 = *reinterpret_cast<const float4*>(src + 4);
      uint4 o;
      o.x = pack2(v0.x, v0.y); o.y = pack2(v0.z, v0.w);
      o.z = pack2(v1.x, v1.y); o.w = pack2(v1.z, v1.w);
      *reinterpret_cast<uint4*>(&W2F[((size_t)(c * 64 + jt) * 64 + lane) * 8]) = o;
    }
  } else if (bid < 113) {
    int mt = bid - 64;
    int col0 = mt * 16;
    int w = t >> 6, lane = t & 63;
    int l15 = lane & 15, quad = lane >> 4;
    for (int cg = 0; cg < 8; cg++) {
      int c = cg * 4 + w;
#pragma unroll
      for (int p = 0; p < 8; p++) {
        int r = p * 4 + (lane >> 4);
        Ts[w][r][lane & 15] = W1[(size_t)(c * 32 + r) * INF + col0 + (lane & 15)];
      }
      float f[8];
#pragma unroll
      for (int e = 0; e < 8; e++) f[e] = Ts[w][quad * 8 + e][l15];
      uint4 o;
      o.x = pack2(f[0], f[1]); o.y = pack2(f[2], f[3]);
      o.z = pack2(f[4], f[5]); o.w = pack2(f[6], f[7]);
      *reinterpret_cast<uint4*>(&W1F[((size_t)(c * 49 + mt) * 64 + lane) * 8]) = o;
    }
  } else if (bid < 1137) {
    int i = bid - 113;
    const float* w = W1 + (size_t)i * INF;
    float acc[B];
#pragma unroll
    for (int b = 0; b < B; b++) acc[b] = 0.f;
    float wabs = 0.f;
    for (int k = t; k < INF; k += 256) {
      float wv = w[k];
      wabs += fabsf(wv);
#pragma unroll
      for (int b = 0; b < B; b++) acc[b] = fmaf(x[b * INF + k], wv, acc[b]);
    }
#pragma unroll
    for (int off = 32; off > 0; off >>= 1) {
#pragma unroll
      for (int b = 0; b < B; b++) acc[b] += __shfl_down(acc[b], off, 64);
      wabs += __shfl_down(wabs, off, 64);
    }
    int wave = t >> 6, lane = t & 63;
    if (lane == 0) {
#pragma unroll
      for (int b = 0; b < B; b++) red[wave][b] = acc[b];
      red[wave][B] = wabs;
    }
    __syncthreads();
    if (t < B) {
      float s = red[0][t] + red[1][t] + red[2][t] + red[3][t];
      float r = EPSV * (red[0][B] + red[1][B] + red[2][B] + red[3][B]);
      float nom = s + b1[i];
      float zl = nom - r, zu = nom + r;
      float d, l;
      if (zl >= 0.f)      { d = 1.f;            l = 0.f; }
      else if (zu > 0.f)  { d = zu / (zu - zl); l = zl;  }
      else                { d = 0.f;            l = 0.f; }
      d1B[(size_t)t * H1 + i] = d;
      t1B[(size_t)t * H1 + i] = d * l;
      dnB[(size_t)t * H1 + i] = d * nom;
    }
  } else {
    int zb = bid - 1137;
    for (int idx = t; idx < 8192; idx += 256) {
      int pos = zb * 8192 + idx;
      if (pos < 55296) Ezero[pos] = 0.f;
    }
  }
}

// ---------------------------------------------------------------------------
// K3: E[j,b] = eps * sum_k | sum_i W1[i,k] * (W2[j,i]*d1[b,i]) |
// r6 tile (best measured: 60.6 us, 98% combined issue).  Per wave: 5 mt x
// 2 jt x 2 b (acc 80 AGPR) @ 3 waves/SIMD — MFMA+VALU pipes of different
// waves overlap.  Tile-space mapped r2/r5/r6/r7/r8: bigger mt hits either
// the 2-wave register wall (latency-bound) or the LDS barrier-drain wall.
// W1F stride 49, 50th tile unused -> grid (10,8,16) covers mt 0..49 with
// block 9 handling tiles 45..49 (45..48 real + 49 absent) — NO: 10*5=50 >
// 49, so guard the last tile via zero pad... r6 used stride 50 pad.  Here
// keep r6's exact stride-50 scheme?  r6 used stride 50 with 1 pad tile; we
// revert to that exact proven layout.
// ---------------------------------------------------------------------------
#define K3_LOAD(c, A, Bv) do {                                                  \
  _Pragma("unroll")                                                             \
  for (int ni = 0; ni < 2; ni++)                                                \
    Bv[ni] = *reinterpret_cast<const uint4*>(bBase + (size_t)(c) * 32768 + ni * 512); \
  _Pragma("unroll")                                                             \
  for (int mi = 0; mi < 5; mi++)                                                \
    A[mi] = *reinterpret_cast<const uint4*>(aBase + (size_t)(c) * 25088 + mi * 512); \
} while (0)

#define K3F_COMP(c, A, Bv, DsRow, accB) do {                                    \
  float4 dv0 = *reinterpret_cast<const float4*>(&DsRow[(c) * 32]);              \
  float4 dv1 = *reinterpret_cast<const float4*>(&DsRow[(c) * 32 + 4]);          \
  short8 bfr[2];                                                                \
  _Pragma("unroll")                                                             \
  for (int ni = 0; ni < 2; ni++) {                                              \
    uint4 sb;                                                                   \
    sb.x = scale_pack(Bv[ni].x, dv0.x, dv0.y);                                  \
    sb.y = scale_pack(Bv[ni].y, dv0.z, dv0.w);                                  \
    sb.z = scale_pack(Bv[ni].z, dv1.x, dv1.y);                                  \
    sb.w = scale_pack(Bv[ni].w, dv1.z, dv1.w);                                  \
    bfr[ni] = __builtin_bit_cast(short8, sb);                                   \
  }                                                                             \
  _Pragma("unroll")                                                             \
  for (int mi = 0; mi < 5; mi++) {                                              \
    short8 af = __builtin_bit_cast(short8, A[mi]);                              \
    _Pragma("unroll")                                                           \
    for (int ni = 0; ni < 2; ni++)                                              \
      accB[mi][ni] = __builtin_amdgcn_mfma_f32_16x16x32_bf16(af, bfr[ni], accB[mi][ni], 0, 0, 0); \
  }                                                                             \
} while (0)

// NOTE: 49 mt-tiles with 5 mt/block x 10 blocks needs stride 49 + last block
// covering tiles 45..49 -> tile 49 doesn't exist.  Simplest proven scheme:
// blockIdx.x in [0,10); blocks 0..8 cover 5 tiles each (0..44); block 9
// covers tiles 44..48 (one tile overlap would DOUBLE-COUNT — wrong).  So we
// keep the r6 zero-pad-tile-50 approach but at stride 49 it breaks.  Hence:
// mt base = bx*5 for bx<9, and bx==9 handles tiles 45..49 where tile 49 is
// out of range.  To avoid all this, A loads for mi beyond 48 read tile 48
// and the MFMA result is discarded? No — accumulates wrongly.
// => Use stride 49 with grid.x = 7 (7 mt/block, r2 k-split)?  That changes
// the k3 tile.  Clean solution: keep stride 49 and grid (10,...) but clamp:
// block 9 processes only 4 tiles (45..48) via runtime masking is divergent.
// PROVEN path: reuse r6's k_pre exactly (stride 50 + 1 zero pad tile).
#undef K3_LOAD
#define K3_LOAD(c, A, Bv) do {                                                  \
  _Pragma("unroll")                                                             \
  for (int ni = 0; ni < 2; ni++)                                                \
    Bv[ni] = *reinterpret_cast<const uint4*>(bBase + (size_t)(c) * 32768 + ni * 512); \
  _Pragma("unroll")                                                             \
  for (int mi = 0; mi < 5; mi++)                                                \
    A[mi] = *reinterpret_cast<const uint4*>(aBase + (size_t)(c) * 25600 + mi * 512); \
} while (0)

__global__ __launch_bounds__(256, 3) void k3(
    const ushort* __restrict__ W1F, const ushort* __restrict__ W2F,
    const float* __restrict__ d1B, float* __restrict__ E)
{
  int b0 = blockIdx.z * 2;
  int t = threadIdx.x, w = t >> 6, lane = t & 63;
  int quad = lane >> 4, l15 = lane & 15;
  int mt0 = blockIdx.x * 5;
  int jt0 = blockIdx.y * 8 + w * 2;

  __shared__ float Ds[2][H1];
  for (int idx = t; idx < 2 * H1; idx += 256)
    Ds[idx >> 10][idx & 1023] = d1B[(size_t)(b0 + (idx >> 10)) * H1 + (idx & 1023)];
  __syncthreads();

  const ushort* aBase = W1F + ((size_t)mt0 * 64 + lane) * 8;
  const ushort* bBase = W2F + ((size_t)jt0 * 64 + lane) * 8;
  const float* Ds0 = &Ds[0][quad * 8];
  const float* Ds1 = &Ds[1][quad * 8];

  floatx4 acc[2][5][2];
#pragma unroll
  for (int bb = 0; bb < 2; bb++)
#pragma unroll
    for (int mi = 0; mi < 5; mi++)
#pragma unroll
      for (int ni = 0; ni < 2; ni++) acc[bb][mi][ni] = (floatx4){0.f, 0.f, 0.f, 0.f};

  uint4 a0[5], b0v[2], a1[5], b1v[2];
  K3_LOAD(0, a0, b0v);
  K3_LOAD(1, a1, b1v);
  for (int c = 0; c < 30; c += 2) {
    K3F_COMP(c, a0, b0v, Ds0, acc[0]);
    K3F_COMP(c, a0, b0v, Ds1, acc[1]);
    K3_LOAD(c + 2, a0, b0v);
    K3F_COMP(c + 1, a1, b1v, Ds0, acc[0]);
    K3F_COMP(c + 1, a1, b1v, Ds1, acc[1]);
    if (c + 3 < 32) K3_LOAD(c + 3, a1, b1v);
  }
  K3F_COMP(30, a0, b0v, Ds0, acc[0]);
  K3F_COMP(30, a0, b0v, Ds1, acc[1]);
  K3F_COMP(31, a1, b1v, Ds0, acc[0]);
  K3F_COMP(31, a1, b1v, Ds1, acc[1]);

#pragma unroll
  for (int bb = 0; bb < 2; bb++) {
#pragma unroll
    for (int ni = 0; ni < 2; ni++) {
      float s = 0.f;
#pragma unroll
      for (int mi = 0; mi < 5; mi++)
#pragma unroll
        for (int r = 0; r < 4; r++) s += fabsf(acc[bb][mi][ni][r]);
      s += __shfl_xor(s, 16, 64);
      s += __shfl_xor(s, 32, 64);
      if (lane < 16) {
        int j = (jt0 + ni) * 16 + l15;
        atomicAdd(&E[(size_t)j * B + b0 + bb], EPSV * s);
      }
    }
  }
}

// k_pre variant for stride-50 W1F (r6 exact): pad tile 49 with zeros.
__global__ __launch_bounds__(256) void k_pre50(
    const float* __restrict__ x, const float* __restrict__ W1,
    const float* __restrict__ b1, const float* __restrict__ W2,
    ushort* __restrict__ W1F, ushort* __restrict__ W2F,
    float* __restrict__ d1B, float* __restrict__ t1B, float* __restrict__ dnB,
    float* __restrict__ Ezero)
{
  __shared__ float red[4][B + 1];
  __shared__ float Ts[4][32][17];
  int bid = blockIdx.x;
  int t = threadIdx.x;
  if (bid < 64) {
    int jt = bid;
    int lane = t & 63, c0 = t >> 6;
    int l15 = lane & 15, quad = lane >> 4;
    for (int c = c0; c < 32; c += 4) {
      const float* src = &W2[(size_t)(jt * 16 + l15) * H1 + c * 32 + quad * 8];
      float4 v0 = *reinterpret_cast<const float4*>(src);
      float4 v1 = *reinterpret_cast<const float4*>(src + 4);
      uint4 o;
      o.x = pack2(v0.x, v0.y); o.y = pack2(v0.z, v0.w);
      o.z = pack2(v1.x, v1.y); o.w = pack2(v1.z, v1.w);
      *reinterpret_cast<uint4*>(&W2F[((size_t)(c * 64 + jt) * 64 + lane) * 8]) = o;
    }
  } else if (bid < 114) {
    int mt = bid - 64;                 // 0..49
    int w = t >> 6, lane = t & 63;
    int l15 = lane & 15, quad = lane >> 4;
    if (mt >= 49) {
      uint4 z; z.x = 0; z.y = 0; z.z = 0; z.w = 0;
      for (int cg = 0; cg < 8; cg++) {
        int c = cg * 4 + w;
        *reinterpret_cast<uint4*>(&W1F[((size_t)(c * 50 + mt) * 64 + lane) * 8]) = z;
      }
    } else {
      int col0 = mt * 16;
      for (int cg = 0; cg < 8; cg++) {
        int c = cg * 4 + w;
#pragma unroll
        for (int p = 0; p < 8; p++) {
          int r = p * 4 + (lane >> 4);
          Ts[w][r][lane & 15] = W1[(size_t)(c * 32 + r) * INF + col0 + (lane & 15)];
        }
        float f[8];
#pragma unroll
        for (int e = 0; e < 8; e++) f[e] = Ts[w][quad * 8 + e][l15];
        uint4 o;
        o.x = pack2(f[0], f[1]); o.y = pack2(f[2], f[3]);
        o.z = pack2(f[4], f[5]); o.w = pack2(f[6], f[7]);
        *reinterpret_cast<uint4*>(&W1F[((size_t)(c * 50 + mt) * 64 + lane) * 8]) = o;
      }
    }
  } else if (bid < 1138) {
    int i = bid - 114;
    const float* w = W1 + (size_t)i * INF;
    float acc[B];
#pragma unroll
    for (int b = 0; b < B; b++) acc[b] = 0.f;
    float wabs = 0.f;
    for (int k = t; k < INF; k += 256) {
      float wv = w[k];
      wabs += fabsf(wv);
#pragma unroll
      for (int b = 0; b < B; b++) acc[b] = fmaf(x[b * INF + k], wv, acc[b]);
    }
#pragma unroll
    for (int off = 32; off > 0; off >>= 1) {
#pragma unroll
      for (int b = 0; b < B; b++) acc[b] += __shfl_down(acc[b], off, 64);
      wabs += __shfl_down(wabs, off, 64);
    }
    int wave = t >> 6, lane = t & 63;
    if (lane == 0) {
#pragma unroll
      for (int b = 0; b < B; b++) red[wave][b] = acc[b];
      red[wave][B] = wabs;
    }
    __syncthreads();
    if (t < B) {
      float s = red[0][t] + red[1][t] + red[2][t] + red[3][t];
      float r = EPSV * (red[0][B] + red[1][B] + red[2][B] + red[3][B]);
      float nom = s + b1[i];
      float zl = nom - r, zu = nom + r;
      float d, l;
      if (zl >= 0.f)      { d = 1.f;            l = 0.f; }
      else if (zu > 0.f)  { d = zu / (zu - zl); l = zl;  }
      else                { d = 0.f;            l = 0.f; }
      d1B[(size_t)t * H1 + i] = d;
      t1B[(size_t)t * H1 + i] = d * l;
      dnB[(size_t)t * H1 + i] = d * nom;
    }
  } else {
    int zb = bid - 1138;
    for (int idx = t; idx < 8192; idx += 256) {
      int pos = zb * 8192 + idx;
      if (pos < 55296) Ezero[pos] = 0.f;
    }
  }
}

// ---------------------------------------------------------------------------
// K245A: fused k2 matvecs + combine + nu2 build.  One block per j (= i2).
// ---------------------------------------------------------------------------
__global__ __launch_bounds__(256) void k245a(
    const float* __restrict__ W2, const float* __restrict__ b2,
    const float* __restrict__ dnB, const float* __restrict__ t1B,
    const float* __restrict__ E, const float* __restrict__ W3,
    const int* __restrict__ y,
    float* __restrict__ nu2T, float* __restrict__ F2)
{
  int j = blockIdx.x;
  int t = threadIdx.x;
  int wave = t >> 6, lane = t & 63;
  int b0 = wave * 8;
  float aA[8] = {}, aCl[8] = {}, aCu[8] = {};
  const float* __restrict__ w2 = W2 + (size_t)j * H1;
  for (int i = lane; i < H1; i += 64) {
    float wv = w2[i];
    float wp = fmaxf(wv, 0.f), wn = fmaxf(-wv, 0.f);
#pragma unroll
    for (int r = 0; r < 8; r++) {
      float dv = dnB[(size_t)(b0 + r) * H1 + i];
      float tv = t1B[(size_t)(b0 + r) * H1 + i];
      aA[r]  = fmaf(wv, dv, aA[r]);
      aCl[r] = fmaf(wn, tv, aCl[r]);
      aCu[r] = fmaf(wp, tv, aCu[r]);
    }
  }
#pragma unroll
  for (int off = 32; off > 0; off >>= 1) {
#pragma unroll
    for (int r = 0; r < 8; r++) {
      aA[r]  += __shfl_down(aA[r],  off, 64);
      aCl[r] += __shfl_down(aCl[r], off, 64);
      aCu[r] += __shfl_down(aCu[r], off, 64);
    }
  }
  __shared__ float sA[B], sCl[B], sCu[B];
  __shared__ float sd2[B], st2[B], sdb[B], swy[B], sw3[NC];
  float bj = b2[j];
  if (lane == 0) {
#pragma unroll
    for (int r = 0; r < 8; r++) {
      sA [b0 + r] = aA[r] + bj;
      sCl[b0 + r] = aCl[r];
      sCu[b0 + r] = aCu[r];
    }
  }
  if (t >= 64 && t < 96)   swy[t - 64]  = W3[(size_t)y[t - 64] * H2 + j];
  if (t >= 128 && t < 138) sw3[t - 128] = W3[(size_t)(t - 128) * H2 + j];
  __syncthreads();
  if (t < B) {
    float a = sA[t], e = E[(size_t)j * B + t];
    float zl = a - e + sCl[t];
    float zu = a + e - sCu[t];
    float d, l;
    if (zl >= 0.f)      { d = 1.f;            l = 0.f; }
    else if (zu > 0.f)  { d = zu / (zu - zl); l = zl;  }
    else                { d = 0.f;            l = 0.f; }
    sd2[t] = d;
    st2[t] = d * l;
    sdb[t] = d * bj;
  }
  __syncthreads();
  for (int tt = t; tt < B * NC; tt += 256) {   // B*NC=320 > 256: strided!
    int b = tt / NC, jc = tt - b * NC;
    float cw = swy[b] - sw3[jc];
    float d2v = sd2[b];
    nu2T[((size_t)b * H2 + j) * 12 + jc] = cw * d2v;
    float val = cw * sdb[b] + fmaxf(-cw, 0.f) * st2[b];
    atomicAdd(&F2[((size_t)(j & 63) * B + b) * NC + jc], val);
  }
}

// ---------------------------------------------------------------------------
// K5b1: hpart[s][b][j][i1] = sum_{i2 in slice s (128)} nu2T[b][i2][j]*W2[i2,i1]
// ---------------------------------------------------------------------------
__global__ __launch_bounds__(256) void k5b1(
    const float* __restrict__ W2, const float* __restrict__ nu2T,
    float* __restrict__ hpart)
{
  int t = threadIdx.x;
  int i1 = blockIdx.x * 512 + t * 2;
  int b = blockIdx.y, s = blockIdx.z;
  const float* __restrict__ nrowb = nu2T + ((size_t)b * H2 + s * 128) * 12;
  const float* __restrict__ w2b = W2 + (size_t)s * 128 * H1 + i1;
  float h0[NC] = {}, h1[NC] = {};
  for (int i2 = 0; i2 < 128; i2++) {
    float2 wv = *reinterpret_cast<const float2*>(&w2b[(size_t)i2 * H1]);
    const float* __restrict__ nrow = nrowb + i2 * 12;
#pragma unroll
    for (int j = 0; j < NC; j++) {
      h0[j] = fmaf(nrow[j], wv.x, h0[j]);
      h1[j] = fmaf(nrow[j], wv.y, h1[j]);
    }
  }
#pragma unroll
  for (int j = 0; j < NC; j++) {
    float2 o; o.x = h0[j]; o.y = h1[j];
    *reinterpret_cast<float2*>(&hpart[(((size_t)s * B + b) * NC + j) * H1 + i1]) = o;
  }
}

// ---------------------------------------------------------------------------
// K5b2: h = sum_s hpart; nu1fT[b][i1][j] = h*d1; F += h*dn + relu(-h)*t1m
// ---------------------------------------------------------------------------
__global__ __launch_bounds__(256) void k5b2(
    const float* __restrict__ hpart,
    const float* __restrict__ d1B, const float* __restrict__ t1B,
    const float* __restrict__ dnB,
    float* __restrict__ nu1fT, float* __restrict__ F)
{
  int t = threadIdx.x;
  int i1 = blockIdx.x * 256 + t;
  int b = blockIdx.y;
  float d1v = d1B[(size_t)b * H1 + i1];
  float t1v = t1B[(size_t)b * H1 + i1];
  float dnv = dnB[(size_t)b * H1 + i1];
  float sn[NC], c1[NC];
#pragma unroll
  for (int j = 0; j < NC; j++) {
    float hv = 0.f;
#pragma unroll
    for (int s = 0; s < 8; s++)
      hv += hpart[(((size_t)s * B + b) * NC + j) * H1 + i1];
    nu1fT[((size_t)b * H1 + i1) * 12 + j] = hv * d1v;
    sn[j] = hv * dnv;
    c1[j] = fmaxf(-hv, 0.f) * t1v;
  }
#pragma unroll
  for (int off = 32; off > 0; off >>= 1) {
#pragma unroll
    for (int j = 0; j < NC; j++) {
      sn[j] += __shfl_down(sn[j], off, 64);
      c1[j] += __shfl_down(c1[j], off, 64);
    }
  }
  __shared__ float red[4][2 * NC];
  int wave = t >> 6, lane = t & 63;
  if (lane == 0) {
#pragma unroll
    for (int j = 0; j < NC; j++) { red[wave][j] = sn[j]; red[wave][NC + j] = c1[j]; }
  }
  __syncthreads();
  if (t < NC) {
    float s = 0.f;
    for (int w = 0; w < 4; w++) s += red[w][t] + red[w][NC + t];
    atomicAdd(&F[b * NC + t], s);
  }
}

// ---------------------------------------------------------------------------
// K5c1: ppart[s][b][j][k] = sum_{i1 in slice s (128)} nu1fT[b][i1][j]*W1[i1,k]
// ---------------------------------------------------------------------------
__global__ __launch_bounds__(128) void k5c1(
    const float* __restrict__ W1, const float* __restrict__ nu1fT,
    float* __restrict__ ppart)
{
  int t = threadIdx.x;
  bool valid = (t < 112);
  int k = blockIdx.x * 112 + (valid ? t : 0);
  int b = blockIdx.y, s = blockIdx.z;
  const float* __restrict__ nrowb = nu1fT + ((size_t)b * H1 + s * 128) * 12;
  const float* __restrict__ w1b = W1 + (size_t)s * 128 * INF + k;
  float acc[NC] = {};
  for (int i1 = 0; i1 < 128; i1++) {
    float w1v = w1b[(size_t)i1 * INF];
    const float* __restrict__ nrow = nrowb + i1 * 12;
#pragma unroll
    for (int j = 0; j < NC; j++) acc[j] = fmaf(nrow[j], w1v, acc[j]);
  }
  if (valid) {
#pragma unroll
    for (int j = 0; j < NC; j++)
      ppart[(((size_t)s * B + b) * NC + j) * INF + k] = acc[j];
  }
}

// ---------------------------------------------------------------------------
// K5c2p: partial Ef — grid (7, B), 128 thr.  Each block: 112 k-columns,
// e[j] = sum_k |sum_s ppart|, block-reduce, atomicAdd into EfB[b][j].
// 224 blocks vs the old 32 -> 7x the parallelism on the 8 MB ppart read.
// ---------------------------------------------------------------------------
__global__ __launch_bounds__(128) void k5c2p(
    const float* __restrict__ ppart, float* __restrict__ EfB)
{
  int t = threadIdx.x;
  bool valid = (t < 112);
  int k = blockIdx.x * 112 + (valid ? t : 0);
  int b = blockIdx.y;
  float e[NC];
#pragma unroll
  for (int j = 0; j < NC; j++) {
    float v = 0.f;
#pragma unroll
    for (int s = 0; s < 8; s++)
      v += ppart[(((size_t)s * B + b) * NC + j) * INF + k];
    e[j] = valid ? fabsf(v) : 0.f;
  }
#pragma unroll
  for (int off = 32; off > 0; off >>= 1) {
#pragma unroll
    for (int j = 0; j < NC; j++) e[j] += __shfl_down(e[j], off, 64);
  }
  __shared__ float red[2][NC];
  int wave = t >> 6, lane = t & 63;
  if (lane == 0) {
#pragma unroll
    for (int j = 0; j < NC; j++) red[wave][j] = e[j];
  }
  __syncthreads();
  if (t < NC) atomicAdd(&EfB[b * NC + t], red[0][t] + red[1][t]);
}

// ---------------------------------------------------------------------------
// K_OUT: final combine, 1 block x 320 threads.
// out = eps*EfB - (F + sum_slots F2 + b3[yb]-b3[jc]).
// ---------------------------------------------------------------------------
__global__ __launch_bounds__(320) void k_out(
    const float* __restrict__ EfB, const float* __restrict__ F,
    const float* __restrict__ F2, const float* __restrict__ b3,
    const int* __restrict__ y, float* __restrict__ out)
{
  int t = threadIdx.x;
  if (t < B * NC) {
    int b = t / NC, j = t - b * NC;
    float s = F[b * NC + j];
    for (int slot = 0; slot < 64; slot++)
      s += F2[((size_t)slot * B + b) * NC + j];
    s += b3[y[b]] - b3[j];
    out[b * NC + j] = EPSV * EfB[b * NC + j] - s;
  }
}

// ---------------------------------------------------------------------------
extern "C" void kernel_launch(void* const* d_in, const int* in_sizes, int n_in,
                              void* d_out, int out_size, void* d_ws, size_t ws_size,
                              hipStream_t stream) {
  const float* x  = (const float*)d_in[0];
  const int*   y  = (const int*)  d_in[1];
  const float* W1 = (const float*)d_in[2];
  const float* b1 = (const float*)d_in[3];
  const float* W2 = (const float*)d_in[4];
  const float* b2 = (const float*)d_in[5];
  const float* W3 = (const float*)d_in[6];
  const float* b3 = (const float*)d_in[7];
  float* out = (float*)d_out;
  float* ws  = (float*)d_ws;

  // ---- workspace layout (floats), with lifetime overlays ----
  float* d1B  = ws;
  float* t1B  = ws + 32768;
  float* dnB  = ws + 65536;
  float* E    = ws + 196608;    // 32768 (zeroed in k_pre)
  float* F    = ws + 229376;    // 320, pad to 1024 (zeroed)
  float* F2   = ws + 230400;    // 64*32*10 = 20480 (zeroed)
  float* EfB  = ws + 250880;    // 320, pad to 1024 (zeroed; zero-range 55296)
  float* nu2T = ws + 328704;    // 393216, k245a -> k5b1 (ends 721920)
  ushort* W2F = (ushort*)(ws + 721920);    // 1048576 us (ends 1246208)
  ushort* W1F = (ushort*)(ws + 1246208);   // 32*50*512 = 819200 us (ends 1655808)
  // overlays (disjoint lifetimes):
  float* nu1fT = ws + 328704;   // over nu2T (k5b2 -> k5c1)
  float* hpart = ws + 721920;   // 8*32*10*1024 = 2621440 f over W2F/W1F (k5b1 -> k5b2)
  float* ppart = ws + 721920;   // 8*32*10*784 = 2007040 f, same region (k5c1 -> k5c2p)

  k_pre50<<<1145, 256, 0, stream>>>(x, W1, b1, W2, W1F, W2F, d1B, t1B, dnB, E);
  k3<<<dim3(10, 8, 16), 256, 0, stream>>>(W1F, W2F, d1B, E);
  k245a<<<H2, 256, 0, stream>>>(W2, b2, dnB, t1B, E, W3, y, nu2T, F2);
  k5b1<<<dim3(2, B, 8), 256, 0, stream>>>(W2, nu2T, hpart);
  k5b2<<<dim3(4, B), 256, 0, stream>>>(hpart, d1B, t1B, dnB, nu1fT, F);
  k5c1<<<dim3(7, B, 8), 128, 0, stream>>>(W1, nu1fT, ppart);
  k5c2p<<<dim3(7, B), 128, 0, stream>>>(ppart, EfB);
  k_out<<<1, 320, 0, stream>>>(EfB, F, F2, b3, y, out);
}